// Round 1
// baseline (760.664 us; speedup 1.0000x reference)
//
#include <hip/hip_runtime.h>
#include <hip/hip_bf16.h>

#define TB 8   // rows per block

// ---------------- setup: fold BN + role contribution into weights/bias -------
__global__ __launch_bounds__(256) void setup_kernel(
    const float* __restrict__ conv_W, const float* __restrict__ conv_b,
    const float* __restrict__ bn_gamma, const float* __restrict__ bn_beta,
    const float* __restrict__ bn_mean, const float* __restrict__ bn_var,
    const float* __restrict__ role_emb,
    float* __restrict__ WcEt,      // [128 e][128 f] = s[f]*conv_W[f][128+e]
    float* __restrict__ bias_af) { // [6 a][128 f]
  int i = blockIdx.x * 256 + threadIdx.x;
  if (i < 128 * 128) {
    int e = i >> 7, f = i & 127;
    float s = bn_gamma[f] * rsqrtf(bn_var[f] + 1e-5f);
    WcEt[e * 128 + f] = s * conv_W[f * 256 + 128 + e];
  } else if (i < 128 * 128 + 6 * 128) {
    int j = i - 128 * 128;
    int a = j >> 7, f = j & 127;
    int role = (a == 5) ? 6 : a;   // ROLES = {0,1,2,3,4,6}
    float s = bn_gamma[f] * rsqrtf(bn_var[f] + 1e-5f);
    float dot = 0.f;
    for (int e = 0; e < 128; ++e)
      dot = fmaf(role_emb[role * 128 + e], conv_W[f * 256 + e], dot);
    bias_af[a * 128 + f] = s * (dot + conv_b[f] - bn_mean[f]) + bn_beta[f];
  }
}

// ---------------- fused main kernel ------------------------------------------
__global__ __launch_bounds__(256) void fused_kernel(
    const int* __restrict__ a_ids, const int* __restrict__ b_ids,
    const int* __restrict__ c_ids, const int* __restrict__ event_ids,
    const float* __restrict__ node_features,
    const float* __restrict__ cond_rel, const float* __restrict__ text,
    const float* __restrict__ entity_emb,
    const float* __restrict__ node_W, const float* __restrict__ node_b,
    const float* __restrict__ gfcn_W, const float* __restrict__ gfcn_b,
    const float* __restrict__ WcEt, const float* __restrict__ bias_af,
    float* __restrict__ out, int B) {
  __shared__ float nfs[TB * 4 * 256];    // gathered node_features; reused as x
  __shared__ float vals[TB * 6 * 128];   // (r, a, e)
  const int t = threadIdx.x;
  const int b0 = blockIdx.x * TB;

  // ---- Phase A: gather node_features rows + cond/text into vals cols 4/5 ----
  {
    float4* nfs4 = (float4*)nfs;
    const float4* nf4 = (const float4*)node_features;
    #pragma unroll
    for (int jj = 0; jj < 8; ++jj) {
      int i = jj * 256 + t;
      int row = i >> 6;          // 0..31  (r*4 + a)
      int q = i & 63;
      int r = row >> 2, a = row & 3;
      const int* p = (a == 0) ? a_ids : (a == 1) ? event_ids
                   : (a == 2) ? b_ids : c_ids;   // stack order: a,event,b,c
      int id = p[b0 + r];
      nfs4[row * 64 + q] = nf4[(size_t)id * 64 + q];
    }
    float4* vals4 = (float4*)vals;
    const float4* c4 = (const float4*)cond_rel;
    const float4* t4 = (const float4*)text;
    #pragma unroll
    for (int jj = 0; jj < 2; ++jj) {
      int i = jj * 256 + t;
      int rr = i >> 5;           // 0..15 (r*2 + c)
      int q = i & 31;
      int r = rr >> 1, c = rr & 1;
      const float4* src = c ? t4 : c4;
      vals4[(r * 6 + 4 + c) * 32 + q] = src[(size_t)(b0 + r) * 32 + q];
    }
  }
  __syncthreads();

  // ---- Phase B: ent = entity_emb + relu(nf @ node_W + node_b) -> vals 0..3 --
  {
    const int e = t & 127;
    const int pg = t >> 7;       // 0: a,event   1: b,c
    const int a0 = pg * 2;
    float acc[TB][2];
    #pragma unroll
    for (int r = 0; r < TB; ++r) { acc[r][0] = 0.f; acc[r][1] = 0.f; }
    const float4* nfs4 = (const float4*)nfs;
    for (int k4 = 0; k4 < 64; ++k4) {
      float w0 = node_W[(k4 * 4 + 0) * 128 + e];
      float w1 = node_W[(k4 * 4 + 1) * 128 + e];
      float w2 = node_W[(k4 * 4 + 2) * 128 + e];
      float w3 = node_W[(k4 * 4 + 3) * 128 + e];
      #pragma unroll
      for (int r = 0; r < TB; ++r) {
        float4 x0 = nfs4[(r * 4 + a0) * 64 + k4];
        float4 x1 = nfs4[(r * 4 + a0 + 1) * 64 + k4];
        acc[r][0] = fmaf(x0.x, w0, fmaf(x0.y, w1, fmaf(x0.z, w2, fmaf(x0.w, w3, acc[r][0]))));
        acc[r][1] = fmaf(x1.x, w0, fmaf(x1.y, w1, fmaf(x1.z, w2, fmaf(x1.w, w3, acc[r][1]))));
      }
    }
    float nb = node_b[e];
    const int* p0 = pg ? b_ids : a_ids;
    const int* p1 = pg ? c_ids : event_ids;
    #pragma unroll
    for (int r = 0; r < TB; ++r) {
      int id0 = p0[b0 + r];
      int id1 = p1[b0 + r];
      vals[(r * 6 + a0) * 128 + e] =
          entity_emb[(size_t)id0 * 128 + e] + fmaxf(acc[r][0] + nb, 0.f);
      vals[(r * 6 + a0 + 1) * 128 + e] =
          entity_emb[(size_t)id1 * 128 + e] + fmaxf(acc[r][1] + nb, 0.f);
    }
  }
  __syncthreads();

  // ---- Phase C: x = relu(vals @ WcEt + bias_af) -> xs (aliases nfs) ---------
  float* xs = nfs;
  {
    const int f = t & 127;
    const int half = t >> 7;     // 0: a=0..2  1: a=3..5
    float xacc[TB][3];
    #pragma unroll
    for (int r = 0; r < TB; ++r)
      #pragma unroll
      for (int j = 0; j < 3; ++j) xacc[r][j] = 0.f;
    const float4* vals4 = (const float4*)vals;
    for (int e4 = 0; e4 < 32; ++e4) {
      float w0 = WcEt[(e4 * 4 + 0) * 128 + f];
      float w1 = WcEt[(e4 * 4 + 1) * 128 + f];
      float w2 = WcEt[(e4 * 4 + 2) * 128 + f];
      float w3 = WcEt[(e4 * 4 + 3) * 128 + f];
      #pragma unroll
      for (int r = 0; r < TB; ++r)
        #pragma unroll
        for (int j = 0; j < 3; ++j) {
          float4 vv = vals4[(r * 6 + half * 3 + j) * 32 + e4];
          xacc[r][j] = fmaf(vv.x, w0, fmaf(vv.y, w1, fmaf(vv.z, w2, fmaf(vv.w, w3, xacc[r][j]))));
        }
    }
    #pragma unroll
    for (int r = 0; r < TB; ++r)
      #pragma unroll
      for (int j = 0; j < 3; ++j) {
        int a = half * 3 + j;
        xs[(r * 6 + a) * 128 + f] = fmaxf(xacc[r][j] + bias_af[a * 128 + f], 0.f);
      }
  }
  __syncthreads();

  // ---- Phase D: umin/vmin over a, then out = relu(umin+vmin+gb) -------------
  {
    const int g = t;             // 0..255
    float u[TB][6], v[TB][6];
    #pragma unroll
    for (int r = 0; r < TB; ++r)
      #pragma unroll
      for (int a = 0; a < 6; ++a) { u[r][a] = 0.f; v[r][a] = 0.f; }
    const float4* xs4 = (const float4*)xs;
    for (int e4 = 0; e4 < 32; ++e4) {
      float w10 = gfcn_W[(e4 * 4 + 0) * 256 + g];
      float w11 = gfcn_W[(e4 * 4 + 1) * 256 + g];
      float w12 = gfcn_W[(e4 * 4 + 2) * 256 + g];
      float w13 = gfcn_W[(e4 * 4 + 3) * 256 + g];
      float w20 = gfcn_W[(128 + e4 * 4 + 0) * 256 + g];
      float w21 = gfcn_W[(128 + e4 * 4 + 1) * 256 + g];
      float w22 = gfcn_W[(128 + e4 * 4 + 2) * 256 + g];
      float w23 = gfcn_W[(128 + e4 * 4 + 3) * 256 + g];
      #pragma unroll
      for (int r = 0; r < TB; ++r)
        #pragma unroll
        for (int a = 0; a < 6; ++a) {
          float4 xv = xs4[(r * 6 + a) * 32 + e4];
          u[r][a] = fmaf(xv.x, w10, fmaf(xv.y, w11, fmaf(xv.z, w12, fmaf(xv.w, w13, u[r][a]))));
          v[r][a] = fmaf(xv.x, w20, fmaf(xv.y, w21, fmaf(xv.z, w22, fmaf(xv.w, w23, v[r][a]))));
        }
    }
    float gbv = gfcn_b[g];
    #pragma unroll
    for (int r = 0; r < TB; ++r) {
      float um = fminf(fminf(fminf(u[r][0], u[r][1]), fminf(u[r][2], u[r][3])),
                       fminf(u[r][4], u[r][5]));
      float vm = fminf(fminf(fminf(v[r][0], v[r][1]), fminf(v[r][2], v[r][3])),
                       fminf(v[r][4], v[r][5]));
      out[(size_t)(b0 + r) * 256 + g] = fmaxf(um + vm + gbv, 0.f);
    }
  }
}

extern "C" void kernel_launch(void* const* d_in, const int* in_sizes, int n_in,
                              void* d_out, int out_size, void* d_ws, size_t ws_size,
                              hipStream_t stream) {
  const int* a_ids         = (const int*)d_in[0];
  const int* b_ids         = (const int*)d_in[1];
  const int* c_ids         = (const int*)d_in[2];
  const int* event_ids     = (const int*)d_in[3];
  const float* node_features = (const float*)d_in[4];
  const float* cond_rel    = (const float*)d_in[5];
  const float* text        = (const float*)d_in[6];
  const float* entity_emb  = (const float*)d_in[7];
  const float* role_emb    = (const float*)d_in[8];
  const float* node_W      = (const float*)d_in[9];
  const float* node_b      = (const float*)d_in[10];
  const float* conv_W      = (const float*)d_in[11];
  const float* conv_b      = (const float*)d_in[12];
  const float* bn_gamma    = (const float*)d_in[13];
  const float* bn_beta     = (const float*)d_in[14];
  const float* bn_mean     = (const float*)d_in[15];
  const float* bn_var      = (const float*)d_in[16];
  const float* gfcn_W      = (const float*)d_in[17];
  const float* gfcn_b      = (const float*)d_in[18];
  float* out = (float*)d_out;

  float* WcEt    = (float*)d_ws;        // 128*128 floats
  float* bias_af = WcEt + 128 * 128;    // 6*128 floats

  const int B = in_sizes[0];            // 32768

  setup_kernel<<<67, 256, 0, stream>>>(conv_W, conv_b, bn_gamma, bn_beta,
                                       bn_mean, bn_var, role_emb, WcEt, bias_af);
  fused_kernel<<<B / TB, 256, 0, stream>>>(
      a_ids, b_ids, c_ids, event_ids, node_features, cond_rel, text, entity_emb,
      node_W, node_b, gfcn_W, gfcn_b, WcEt, bias_af, out, B);
}

// Round 2
// 254.452 us; speedup vs baseline: 2.9894x; 2.9894x over previous
//
#include <hip/hip_runtime.h>
#include <hip/hip_bf16.h>

typedef short bf16x8 __attribute__((ext_vector_type(8)));
typedef float f32x4 __attribute__((ext_vector_type(4)));
#define MFMA16 __builtin_amdgcn_mfma_f32_16x16x32_bf16

// ---- split-bf16 helpers -----------------------------------------------------
__device__ __forceinline__ unsigned short rne_bf16(float f) {
  unsigned u = __builtin_bit_cast(unsigned, f);
  return (unsigned short)((u + 0x7fffu + ((u >> 16) & 1u)) >> 16);
}
__device__ __forceinline__ float bf16f(unsigned short h) {
  unsigned u = ((unsigned)h) << 16;
  return __builtin_bit_cast(float, u);
}
__device__ __forceinline__ void split2(float f, short& h, short& l) {
  unsigned short hh = rne_bf16(f);
  h = (short)hh;
  l = (short)rne_bf16(f - bf16f(hh));
}

// ---- ws layout (short offsets) ----------------------------------------------
constexpr int NW_SH = 32768;   // node_W  256x128
constexpr int WC_SH = 16384;   // WcEt    128x128
constexpr int GF_SH = 65536;   // gfcn    128x512
constexpr int OFF_NWH = 0;
constexpr int OFF_NWL = NW_SH;
constexpr int OFF_WCH = 2 * NW_SH;
constexpr int OFF_WCL = 2 * NW_SH + WC_SH;
constexpr int OFF_GFH = 2 * NW_SH + 2 * WC_SH;
constexpr int OFF_GFL = 2 * NW_SH + 2 * WC_SH + GF_SH;
constexpr size_t OFF_BIAS_BYTES = (size_t)(2 * NW_SH + 2 * WC_SH + 2 * GF_SH) * 2;

// ---- setup: pack weights into MFMA fragment layout (hi/lo bf16 planes) ------
// packed[nf][kf][lane][j] = W[kf*32 + (lane>>4)*8 + j][nf*16 + (lane&15)]
__global__ __launch_bounds__(256) void setup_kernel(
    const float* __restrict__ node_W, const float* __restrict__ conv_W,
    const float* __restrict__ gfcn_W, const float* __restrict__ role_emb,
    const float* __restrict__ conv_b, const float* __restrict__ bn_gamma,
    const float* __restrict__ bn_beta, const float* __restrict__ bn_mean,
    const float* __restrict__ bn_var, short* __restrict__ wsS,
    float* __restrict__ bias_af) {
  int idx = blockIdx.x * 256 + threadIdx.x;
  int stride = gridDim.x * 256;
  for (int i = idx; i < 115456; i += stride) {
    if (i < 114688) {
      int j = i & 7, lane = (i >> 3) & 63;
      int kq = ((lane >> 4) & 3) * 8 + j, n16 = lane & 15;
      float val;
      short *ph, *pl;
      int loc;
      if (i < NW_SH) {
        loc = i;
        int f = i >> 9, kf = f & 7, nfr = f >> 3;
        int k = kf * 32 + kq, n = nfr * 16 + n16;
        val = node_W[k * 128 + n];
        ph = wsS + OFF_NWH; pl = wsS + OFF_NWL;
      } else if (i < NW_SH + WC_SH) {
        loc = i - NW_SH;
        int f = loc >> 9, kf = f & 3, nfr = f >> 2;
        int k = kf * 32 + kq, n = nfr * 16 + n16;
        float s = bn_gamma[n] * rsqrtf(bn_var[n] + 1e-5f);
        val = s * conv_W[n * 256 + 128 + k];     // WcEt[e=k][f=n]
        ph = wsS + OFF_WCH; pl = wsS + OFF_WCL;
      } else {
        loc = i - NW_SH - WC_SH;
        int f = loc >> 9, kf = f & 3, nfr = f >> 2;   // nfr 0..31
        int k = kf * 32 + kq, n = nfr * 16 + n16;     // n 0..511
        val = (n < 256) ? gfcn_W[k * 256 + n]
                        : gfcn_W[(128 + k) * 256 + (n - 256)];
        ph = wsS + OFF_GFH; pl = wsS + OFF_GFL;
      }
      short h, l;
      split2(val, h, l);
      ph[loc] = h; pl[loc] = l;
    } else {
      int loc = i - 114688;
      int a = loc >> 7, fc = loc & 127;
      int role = (a == 5) ? 6 : a;   // ROLES = {0,1,2,3,4,6}
      float s = bn_gamma[fc] * rsqrtf(bn_var[fc] + 1e-5f);
      float dot = 0.f;
      for (int e = 0; e < 128; ++e)
        dot = fmaf(role_emb[role * 128 + e], conv_W[fc * 256 + e], dot);
      bias_af[loc] = s * (dot + conv_b[fc] - bn_mean[fc]) + bn_beta[fc];
    }
  }
}

// ---- fused main kernel: 16 rows/block, 4 waves ------------------------------
__global__ __launch_bounds__(256) void fused_kernel(
    const int* __restrict__ a_ids, const int* __restrict__ b_ids,
    const int* __restrict__ c_ids, const int* __restrict__ event_ids,
    const float* __restrict__ nf, const float* __restrict__ cond,
    const float* __restrict__ text, const float* __restrict__ ent,
    const float* __restrict__ node_b, const float* __restrict__ gfcn_b,
    const short* __restrict__ wsS, const float* __restrict__ bias_af,
    float* __restrict__ out) {
  __shared__ __align__(16) unsigned char smem[49408];
  short* lds_hi = (short*)smem;                 // 96x128 bf16 hi plane
  short* lds_lo = (short*)(smem + 24576);       // lo plane
  int* ids_s = (int*)(smem + 49152);            // 64 ids
  float* umin_s = (float*)smem;                 // overlay after x dead
  float* vmin_s = (float*)(smem + 16384);

  const int t = threadIdx.x;
  const int wv = t >> 6, lane = t & 63;
  const int r15 = lane & 15, q = lane >> 4;
  const int b0 = blockIdx.x * 16;

  const bf16x8* nwh = (const bf16x8*)(wsS + OFF_NWH);
  const bf16x8* nwl = (const bf16x8*)(wsS + OFF_NWL);
  const bf16x8* wch = (const bf16x8*)(wsS + OFF_WCH);
  const bf16x8* wcl = (const bf16x8*)(wsS + OFF_WCL);
  const bf16x8* gfh = (const bf16x8*)(wsS + OFF_GFH);
  const bf16x8* gfl = (const bf16x8*)(wsS + OFF_GFL);

  if (t < 64) {
    int a = t >> 4, r = t & 15;
    const int* p = (a == 0) ? a_ids : (a == 1) ? event_ids
                 : (a == 2) ? b_ids : c_ids;    // stack: a,event,b,c
    ids_s[t] = p[b0 + r];
  }
  __syncthreads();

  // ---- cond_rel/text rows (a=4,5) -> planes ----
  #pragma unroll
  for (int j = 0; j < 16; ++j) {
    int i = j * 256 + t;
    int arr = i >> 11, rem = i & 2047, r = rem >> 7, e = rem & 127;
    const float* src = arr ? text : cond;
    float v = src[(size_t)(b0 + r) * 128 + e];
    short h, l;
    split2(v, h, l);
    int row = (4 + arr) * 16 + r;
    int si = row * 128 + (e ^ ((row & 7) << 3));
    lds_hi[si] = h; lds_lo[si] = l;
  }

  // ---- Stage B: vals[a] = entity + relu(nf@node_W + node_b), a = wave -------
  {
    int my_id = ids_s[wv * 16 + r15];
    int eid[4];
    #pragma unroll
    for (int rg = 0; rg < 4; ++rg) eid[rg] = ids_s[wv * 16 + q * 4 + rg];
    const float* arow = nf + (size_t)my_id * 256 + q * 8;
    bf16x8 Ah[8], Al[8];
    #pragma unroll
    for (int ks = 0; ks < 8; ++ks) {
      float av[8];
      *(float4*)&av[0] = *(const float4*)(arow + ks * 32);
      *(float4*)&av[4] = *(const float4*)(arow + ks * 32 + 4);
      #pragma unroll
      for (int j = 0; j < 8; ++j) {
        short h, l; split2(av[j], h, l);
        Ah[ks][j] = h; Al[ks][j] = l;
      }
    }
    for (int n8 = 0; n8 < 8; ++n8) {
      f32x4 acc = {0.f, 0.f, 0.f, 0.f};
      #pragma unroll
      for (int ks = 0; ks < 8; ++ks) {
        bf16x8 bh = nwh[(n8 * 8 + ks) * 64 + lane];
        bf16x8 bl = nwl[(n8 * 8 + ks) * 64 + lane];
        acc = MFMA16(Ah[ks], bh, acc, 0, 0, 0);
        acc = MFMA16(Al[ks], bh, acc, 0, 0, 0);
        acc = MFMA16(Ah[ks], bl, acc, 0, 0, 0);
      }
      int col = n8 * 16 + r15;
      float nb = node_b[col];
      #pragma unroll
      for (int rg = 0; rg < 4; ++rg) {
        float e0 = ent[(size_t)eid[rg] * 128 + col];
        float v = e0 + fmaxf(acc[rg] + nb, 0.f);
        short h, l; split2(v, h, l);
        int row = wv * 16 + q * 4 + rg;
        int si = row * 128 + (col ^ ((row & 7) << 3));
        lds_hi[si] = h; lds_lo[si] = l;
      }
    }
  }
  __syncthreads();

  // ---- Stage C: x = relu(vals @ WcEt + bias_af), wave owns 2 N-frags --------
  f32x4 xacc[6][2];
  #pragma unroll
  for (int a = 0; a < 6; ++a) {
    xacc[a][0] = (f32x4){0.f, 0.f, 0.f, 0.f};
    xacc[a][1] = (f32x4){0.f, 0.f, 0.f, 0.f};
  }
  #pragma unroll
  for (int ks = 0; ks < 4; ++ks) {
    bf16x8 ah[6], al[6];
    int k0 = ks * 32 + q * 8;
    #pragma unroll
    for (int a = 0; a < 6; ++a) {
      int row = a * 16 + r15;
      int si = row * 128 + (k0 ^ ((row & 7) << 3));
      ah[a] = *(const bf16x8*)&lds_hi[si];
      al[a] = *(const bf16x8*)&lds_lo[si];
    }
    #pragma unroll
    for (int jn = 0; jn < 2; ++jn) {
      int nf4 = wv * 2 + jn;
      bf16x8 bh = wch[(nf4 * 4 + ks) * 64 + lane];
      bf16x8 bl = wcl[(nf4 * 4 + ks) * 64 + lane];
      #pragma unroll
      for (int a = 0; a < 6; ++a) {
        xacc[a][jn] = MFMA16(ah[a], bh, xacc[a][jn], 0, 0, 0);
        xacc[a][jn] = MFMA16(al[a], bh, xacc[a][jn], 0, 0, 0);
        xacc[a][jn] = MFMA16(ah[a], bl, xacc[a][jn], 0, 0, 0);
      }
    }
  }
  __syncthreads();   // all vals reads done
  #pragma unroll
  for (int a = 0; a < 6; ++a) {
    #pragma unroll
    for (int jn = 0; jn < 2; ++jn) {
      int col = (wv * 2 + jn) * 16 + r15;
      float bv = bias_af[a * 128 + col];
      #pragma unroll
      for (int rg = 0; rg < 4; ++rg) {
        float v = fmaxf(xacc[a][jn][rg] + bv, 0.f);
        short h, l; split2(v, h, l);
        int row = a * 16 + q * 4 + rg;
        int si = row * 128 + (col ^ ((row & 7) << 3));
        lds_hi[si] = h; lds_lo[si] = l;
      }
    }
  }
  __syncthreads();

  // ---- Stage D: u/v = x @ gfcn, min over a (= per-lane min over M-frags) ----
  f32x4 mreg[8];
  #pragma unroll
  for (int grp = 0; grp < 2; ++grp) {
    f32x4 acc[6][4];
    #pragma unroll
    for (int a = 0; a < 6; ++a)
      #pragma unroll
      for (int jn = 0; jn < 4; ++jn) acc[a][jn] = (f32x4){0.f, 0.f, 0.f, 0.f};
    #pragma unroll
    for (int ks = 0; ks < 4; ++ks) {
      bf16x8 ah[6], al[6];
      int k0 = ks * 32 + q * 8;
      #pragma unroll
      for (int a = 0; a < 6; ++a) {
        int row = a * 16 + r15;
        int si = row * 128 + (k0 ^ ((row & 7) << 3));
        ah[a] = *(const bf16x8*)&lds_hi[si];
        al[a] = *(const bf16x8*)&lds_lo[si];
      }
      #pragma unroll
      for (int jn = 0; jn < 4; ++jn) {
        int nfg = wv * 8 + grp * 4 + jn;
        bf16x8 bh = gfh[(nfg * 4 + ks) * 64 + lane];
        bf16x8 bl = gfl[(nfg * 4 + ks) * 64 + lane];
        #pragma unroll
        for (int a = 0; a < 6; ++a) {
          acc[a][jn] = MFMA16(ah[a], bh, acc[a][jn], 0, 0, 0);
          acc[a][jn] = MFMA16(al[a], bh, acc[a][jn], 0, 0, 0);
          acc[a][jn] = MFMA16(ah[a], bl, acc[a][jn], 0, 0, 0);
        }
      }
    }
    #pragma unroll
    for (int jn = 0; jn < 4; ++jn) {
      #pragma unroll
      for (int rg = 0; rg < 4; ++rg) {
        float mm = acc[0][jn][rg];
        #pragma unroll
        for (int a = 1; a < 6; ++a) mm = fminf(mm, acc[a][jn][rg]);
        mreg[grp * 4 + jn][rg] = mm;
      }
    }
  }
  __syncthreads();   // all x reads done; planes now dead
  {
    float* dst = (wv >= 2) ? vmin_s : umin_s;
    int cbase = (wv & 1) * 128;
    #pragma unroll
    for (int j = 0; j < 8; ++j) {
      int colg = cbase + j * 16 + r15;
      #pragma unroll
      for (int rg = 0; rg < 4; ++rg)
        dst[(q * 4 + rg) * 256 + colg] = mreg[j][rg];
    }
  }
  __syncthreads();
  #pragma unroll
  for (int j = 0; j < 16; ++j) {
    int i = j * 256 + t;
    int r = i >> 8, g = i & 255;
    out[(size_t)(b0 + r) * 256 + g] =
        fmaxf(umin_s[r * 256 + g] + vmin_s[r * 256 + g] + gfcn_b[g], 0.f);
  }
}

extern "C" void kernel_launch(void* const* d_in, const int* in_sizes, int n_in,
                              void* d_out, int out_size, void* d_ws, size_t ws_size,
                              hipStream_t stream) {
  const int* a_ids = (const int*)d_in[0];
  const int* b_ids = (const int*)d_in[1];
  const int* c_ids = (const int*)d_in[2];
  const int* event_ids = (const int*)d_in[3];
  const float* node_features = (const float*)d_in[4];
  const float* cond_rel = (const float*)d_in[5];
  const float* text = (const float*)d_in[6];
  const float* entity_emb = (const float*)d_in[7];
  const float* role_emb = (const float*)d_in[8];
  const float* node_W = (const float*)d_in[9];
  const float* node_b = (const float*)d_in[10];
  const float* conv_W = (const float*)d_in[11];
  const float* conv_b = (const float*)d_in[12];
  const float* bn_gamma = (const float*)d_in[13];
  const float* bn_beta = (const float*)d_in[14];
  const float* bn_mean = (const float*)d_in[15];
  const float* bn_var = (const float*)d_in[16];
  const float* gfcn_W = (const float*)d_in[17];
  const float* gfcn_b = (const float*)d_in[18];
  float* out = (float*)d_out;

  short* wsS = (short*)d_ws;
  float* bias_af = (float*)((char*)d_ws + OFF_BIAS_BYTES);
  const int B = in_sizes[0];   // 32768

  setup_kernel<<<452, 256, 0, stream>>>(node_W, conv_W, gfcn_W, role_emb,
                                        conv_b, bn_gamma, bn_beta, bn_mean,
                                        bn_var, wsS, bias_af);
  fused_kernel<<<B / 16, 256, 0, stream>>>(
      a_ids, b_ids, c_ids, event_ids, node_features, cond_rel, text,
      entity_emb, node_b, gfcn_b, wsS, bias_af, out);
}